// Round 10
// baseline (972.678 us; speedup 1.0000x reference)
//
#include <hip/hip_runtime.h>

#define BN_EPS 1e-5f

typedef unsigned long long u64;

// ---------------- shared-memory union ----------------
struct FpsSm {
  u64    slotK[2][4];    // per-wave candidate key {dist_bits,~j}, parity-buffered
  float4 P4[2048];       // packed point coords for winner gather (1 ds_read_b128)
  float  sel1[3 * 1024];
  float  sel2[3 * 512];
};
struct FeatSm {
  float W1s[256];        // folded layer-1 weights: [c][4] = a*w0,a*w1,a*w2, be-a*mean
  float h1s[128][68];    // padded rows (68 floats = 272B, 16B aligned)
  float stat[4][64][8];  // per-wave partial stats
};
union __align__(16) SMem { FpsSm fps; FeatSm feat; };

// ---------------- fast wave-wide reduce (DPP) ----------------
#if __has_builtin(__builtin_amdgcn_update_dpp) && __has_builtin(__builtin_amdgcn_readlane)
template<int CTRL>
__device__ __forceinline__ float dppmax(float x) {
  const int t = __builtin_amdgcn_update_dpp(0, __float_as_int(x), CTRL, 0xf, 0xf, true);
  return fmaxf(x, __int_as_float(t));
}
__device__ __forceinline__ float wave_max_f32(float x) {
  x = dppmax<0x111>(x); x = dppmax<0x112>(x); x = dppmax<0x114>(x);
  x = dppmax<0x118>(x); x = dppmax<0x142>(x); x = dppmax<0x143>(x);
  return __int_as_float(__builtin_amdgcn_readlane(__float_as_int(x), 63));
}
template<int CTRL>
__device__ __forceinline__ float dppsum(float x) {
  const int t = __builtin_amdgcn_update_dpp(0, __float_as_int(x), CTRL, 0xf, 0xf, true);
  return x + __int_as_float(t);
}
__device__ __forceinline__ float wave_sum_f32(float x) {
  x = dppsum<0x111>(x); x = dppsum<0x112>(x); x = dppsum<0x114>(x);
  x = dppsum<0x118>(x); x = dppsum<0x142>(x); x = dppsum<0x143>(x);
  return __int_as_float(__builtin_amdgcn_readlane(__float_as_int(x), 63));
}
#else
__device__ __forceinline__ float wave_max_f32(float x) {
  for (int off = 32; off; off >>= 1) x = fmaxf(x, __shfl_xor(x, off));
  return x;
}
__device__ __forceinline__ float wave_sum_f32(float x) {
  for (int off = 32; off; off >>= 1) x += __shfl_xor(x, off);
  return x;
}
#endif

// per-lane argmax over R slots, tree-structured (depth log2 R), ties -> lowest slot.
// Exactly matches the serial "if (v > best)" ascending scan.
template<int R>
__device__ __forceinline__ void tree_argmax(const float* __restrict__ mv, float& bv, int& bi) {
  float tv[R]; int ti[R];
#pragma unroll
  for (int i = 0; i < R; i++) { tv[i] = mv[i]; ti[i] = i; }
#pragma unroll
  for (int s = 1; s < R; s <<= 1) {
#pragma unroll
    for (int i = 0; i < R; i += 2*s) {
      const bool up = tv[i+s] > tv[i];     // strict: tie keeps lower (contiguous-range merge)
      tv[i] = up ? tv[i+s] : tv[i];
      ti[i] = up ? ti[i+s] : ti[i];
    }
  }
  bv = tv[0]; bi = ti[0];
}

// ---------------- one FPS phase: 4 waves, barrier exchange, key-only publish ----------------
template<int NPTS>
__device__ void fps_phase(const float* __restrict__ src, float* __restrict__ selOut, FpsSm* sm) {
  constexpr int R = NPTS / 256;
  constexpr int M = NPTS / 2;
  const int tid = threadIdx.x;
  const int w   = tid >> 6;

  float px[R], py[R], pz[R], mind[R];
#pragma unroll
  for (int i = 0; i < R; i++) {
    const int j = tid + 256 * i;
    const float x = src[3*j], y = src[3*j+1], z = src[3*j+2];
    px[i] = x; py[i] = y; pz[i] = z;
    sm->P4[j] = make_float4(x, y, z, 0.f);
  }

  float sx = src[0], sy = src[1], sz = src[2];
  if (tid == 0) { selOut[0] = sx; selOut[1] = sy; selOut[2] = sz; }

  float bv; int bi;
  {
    float mv[R];
#pragma unroll
    for (int i = 0; i < R; i++) {
      const float dx = px[i]-sx, dy = py[i]-sy, dz = pz[i]-sz;
      const float d = __fadd_rn(__fadd_rn(__fmul_rn(dx,dx), __fmul_rn(dy,dy)), __fmul_rn(dz,dz));
      mind[i] = d; mv[i] = d;
    }
    tree_argmax<R>(mv, bv, bi);
  }

  for (int it = 1; it < M; ++it) {
    // wave-level: value max via DPP; winner lane self-identifies
    const float smax = wave_max_f32(bv);
    bool win = (bv == smax);
    if (__popcll(__ballot(win)) > 1) {  // exact value ties (rare): lowest global j wins
      int jj = win ? (tid + (bi << 8)) : 0x7fffffff;
#pragma unroll
      for (int off = 32; off; off >>= 1) jj = min(jj, __shfl_xor(jj, off));
      win = win && ((tid + (bi << 8)) == jj);
    }

    // publish: single u64 key {dist_bits, ~j}; dist>=0 so float-bit order == value order
    const int par = it & 1;
    if (win) {
      const unsigned wj = (unsigned)(tid + (bi << 8));
      sm->slotK[par][w] = ((u64)__float_as_uint(bv) << 32) | (u64)(~wj);
    }
    __syncthreads();

    // combine 4 keys (max = farthest; ties -> lowest j), then coords by index
    const uint4 s01 = *reinterpret_cast<const uint4*>(&sm->slotK[par][0]);
    const uint4 s23 = *reinterpret_cast<const uint4*>(&sm->slotK[par][2]);
    const u64 K0 = ((u64)s01.y << 32) | s01.x;
    const u64 K1 = ((u64)s01.w << 32) | s01.z;
    const u64 K2 = ((u64)s23.y << 32) | s23.x;
    const u64 K3 = ((u64)s23.w << 32) | s23.z;
    const u64 Ka = K0 > K1 ? K0 : K1;
    const u64 Kb = K2 > K3 ? K2 : K3;
    const u64 KW = Ka > Kb ? Ka : Kb;
    const unsigned wj = ~(unsigned)(KW & 0xffffffffu);
    const float4 c = sm->P4[wj];        // broadcast ds_read_b128
    sx = c.x; sy = c.y; sz = c.z;

    if (tid == 0) { selOut[3*it] = sx; selOut[3*it+1] = sy; selOut[3*it+2] = sz; }

    // distance update (independent per slot) + tree argmax (shallow dependency)
    {
      float mv[R];
#pragma unroll
      for (int i = 0; i < R; i++) {
        const float dx = px[i]-sx, dy = py[i]-sy, dz = pz[i]-sz;
        const float d = __fadd_rn(__fadd_rn(__fmul_rn(dx,dx), __fmul_rn(dy,dy)), __fmul_rn(dz,dz));
        const float m = fminf(mind[i], d);
        mind[i] = m; mv[i] = m;
      }
      tree_argmax<R>(mv, bv, bi);
    }
  }
}

// moments of a selected set in LDS (wave 0 only), stored TRANSPOSED: momT[k*S + b]
__device__ void mom_from_sel(const float* __restrict__ sel, int M, float* __restrict__ momT,
                             int S, int b, int lane) {
  float m0=0.f,m1=0.f,m2=0.f,m3=0.f,m4=0.f,m5=0.f,m6=0.f,m7=0.f,m8=0.f;
  for (int k = lane; k < M; k += 64) {
    const float x = sel[3*k], y = sel[3*k+1], z = sel[3*k+2];
    m0 += x; m1 += y; m2 += z;
    m3 = fmaf(x,x,m3); m4 = fmaf(y,y,m4); m5 = fmaf(z,z,m5);
    m6 = fmaf(x,y,m6); m7 = fmaf(x,z,m7); m8 = fmaf(y,z,m8);
  }
#pragma unroll
  for (int off = 32; off; off >>= 1) {
    m0 += __shfl_xor(m0, off); m1 += __shfl_xor(m1, off); m2 += __shfl_xor(m2, off);
    m3 += __shfl_xor(m3, off); m4 += __shfl_xor(m4, off); m5 += __shfl_xor(m5, off);
    m6 += __shfl_xor(m6, off); m7 += __shfl_xor(m7, off); m8 += __shfl_xor(m8, off);
  }
  if (lane == 0) {
    momT[0*S+b]=m0; momT[1*S+b]=m1; momT[2*S+b]=m2; momT[3*S+b]=m3; momT[4*S+b]=m4;
    momT[5*S+b]=m5; momT[6*S+b]=m6; momT[7*S+b]=m7; momT[8*S+b]=m8;
  }
}

// FPS chain: level-0 FPS then level-1 FPS on the selected set (still in LDS)
__device__ void fps_chain(const float* __restrict__ pts, float* __restrict__ pts1,
                          float* __restrict__ pts2, float* __restrict__ momT1,
                          float* __restrict__ momT2, FpsSm* sm) {
  const int b = blockIdx.x, tid = threadIdx.x, lane = tid & 63, w = tid >> 6;
  __builtin_amdgcn_s_setprio(1);

  fps_phase<2048>(pts + (size_t)b * 2048 * 3, sm->sel1, sm);
  __syncthreads();                       // sel1 complete
  {
    float* o = pts1 + (size_t)b * 1024 * 3;
#pragma unroll 4
    for (int e = tid; e < 3 * 1024; e += 256) o[e] = sm->sel1[e];
    if (w == 0) mom_from_sel(sm->sel1, 1024, momT1, 64, b, lane);
  }
  __syncthreads();

  fps_phase<1024>(sm->sel1, sm->sel2, sm);
  __syncthreads();                       // sel2 complete
  {
    float* o = pts2 + (size_t)b * 512 * 3;
#pragma unroll 4
    for (int e = tid; e < 3 * 512; e += 256) o[e] = sm->sel2[e];
    if (w == 0) mom_from_sel(sm->sel2, 512, momT2, 64, b, lane);
  }
  __builtin_amdgcn_s_setprio(0);
}

// ---------------- feature pass with inline BN1-fold (fin1) from transposed moments ----------------
template<int NPTS, int S>
__device__ void featB_body(const float* __restrict__ pts, const float* __restrict__ momT,
                           float Pinv, const float* __restrict__ w1lv,
                           const float* __restrict__ g1lv, const float* __restrict__ be1lv,
                           const float* __restrict__ w2lv, float* __restrict__ partialsB,
                           int fbid, FeatSm* sm) {
  const int tid  = threadIdx.x;
  const int lane = tid & 63;
  const int w    = tid >> 6;
  constexpr int BPB = NPTS / 256;
  const int b = fbid / BPB;
  const size_t pbase = (size_t)b * NPTS + (size_t)(fbid % BPB) * 256;

  // wave 0: fold BN1 into weights (9 DPP wave-sums over moment partials)
  if (w == 0) {
    float Mk[9];
#pragma unroll
    for (int k = 0; k < 9; k++) {
      float v = momT[k*S + lane];
      if (S == 128) v += momT[k*S + 64 + lane];
      Mk[k] = wave_sum_f32(v);
    }
    const int t = lane;
    const float w0 = w1lv[t], w1_ = w1lv[64 + t], w2_ = w1lv[128 + t];
    const float mean = (w0*Mk[0] + w1_*Mk[1] + w2_*Mk[2]) * Pinv;
    const float ey2  = (w0*w0*Mk[3] + w1_*w1_*Mk[4] + w2_*w2_*Mk[5]
                      + 2.f*(w0*w1_*Mk[6] + w0*w2_*Mk[7] + w1_*w2_*Mk[8])) * Pinv;
    const float var  = fmaxf(ey2 - mean*mean, 0.f);
    const float a    = g1lv[t] * rsqrtf(var + BN_EPS);
    float4 r; r.x = a*w0; r.y = a*w1_; r.z = a*w2_; r.w = fmaf(-a, mean, be1lv[t]);
    *reinterpret_cast<float4*>(&sm->W1s[t*4]) = r;
  }
  __syncthreads();

  float wA[64], wB[64];
#pragma unroll
  for (int k = 0; k < 64; k++) { wA[k] = w2lv[k*128 + lane]; wB[k] = w2lv[k*128 + 64 + lane]; }

  float sA=0.f, qA=0.f, sB=0.f, qB=0.f;
  float mxA=-1e30f, mnA=1e30f, mxB=-1e30f, mnB=1e30f;

  for (int r = 0; r < 2; r++) {
    __syncthreads();
    if (tid < 128) {
      const float* pp = pts + (pbase + (size_t)r*128 + tid) * 3;
      const float x = pp[0], y = pp[1], z = pp[2];
#pragma unroll
      for (int k = 0; k < 64; k += 4) {
        float4 hv;
        { const float4 wf = *reinterpret_cast<const float4*>(&sm->W1s[4*(k  )]);
          hv.x = fmaxf(0.f, fmaf(x,wf.x, fmaf(y,wf.y, fmaf(z,wf.z, wf.w)))); }
        { const float4 wf = *reinterpret_cast<const float4*>(&sm->W1s[4*(k+1)]);
          hv.y = fmaxf(0.f, fmaf(x,wf.x, fmaf(y,wf.y, fmaf(z,wf.z, wf.w)))); }
        { const float4 wf = *reinterpret_cast<const float4*>(&sm->W1s[4*(k+2)]);
          hv.z = fmaxf(0.f, fmaf(x,wf.x, fmaf(y,wf.y, fmaf(z,wf.z, wf.w)))); }
        { const float4 wf = *reinterpret_cast<const float4*>(&sm->W1s[4*(k+3)]);
          hv.w = fmaxf(0.f, fmaf(x,wf.x, fmaf(y,wf.y, fmaf(z,wf.z, wf.w)))); }
        *reinterpret_cast<float4*>(&sm->h1s[tid][k]) = hv;
      }
    }
    __syncthreads();
    const int row0 = w * 32;
    for (int p = row0; p < row0 + 32; ++p) {
      float ya = 0.f, yb = 0.f;
#pragma unroll
      for (int k = 0; k < 64; k += 4) {
        const float4 hv = *reinterpret_cast<const float4*>(&sm->h1s[p][k]);
        ya = fmaf(hv.x, wA[k  ], ya);  yb = fmaf(hv.x, wB[k  ], yb);
        ya = fmaf(hv.y, wA[k+1], ya);  yb = fmaf(hv.y, wB[k+1], yb);
        ya = fmaf(hv.z, wA[k+2], ya);  yb = fmaf(hv.z, wB[k+2], yb);
        ya = fmaf(hv.w, wA[k+3], ya);  yb = fmaf(hv.w, wB[k+3], yb);
      }
      sA += ya; qA = fmaf(ya,ya,qA); mxA = fmaxf(mxA,ya); mnA = fminf(mnA,ya);
      sB += yb; qB = fmaf(yb,yb,qB); mxB = fmaxf(mxB,yb); mnB = fminf(mnB,yb);
    }
  }

  float4* st = reinterpret_cast<float4*>(&sm->stat[w][lane][0]);
  st[0] = make_float4(sA,qA,mxA,mnA);
  st[1] = make_float4(sB,qB,mxB,mnB);
  __syncthreads();
  if (w == 0) {
    float4 aA = *reinterpret_cast<float4*>(&sm->stat[0][lane][0]);
    float4 aB = *reinterpret_cast<float4*>(&sm->stat[0][lane][4]);
#pragma unroll
    for (int q = 1; q < 4; q++) {
      const float4 cA = *reinterpret_cast<float4*>(&sm->stat[q][lane][0]);
      const float4 cB = *reinterpret_cast<float4*>(&sm->stat[q][lane][4]);
      aA.x += cA.x; aA.y += cA.y; aA.z = fmaxf(aA.z,cA.z); aA.w = fminf(aA.w,cA.w);
      aB.x += cB.x; aB.y += cB.y; aB.z = fmaxf(aB.z,cB.z); aB.w = fminf(aB.w,cB.w);
    }
    float* pb = partialsB + (size_t)fbid * 512;
    pb[0*128 +      lane] = aA.x; pb[1*128 +      lane] = aA.y;
    pb[2*128 +      lane] = aA.z; pb[3*128 +      lane] = aA.w;
    pb[0*128 + 64 + lane] = aB.x; pb[1*128 + 64 + lane] = aB.y;
    pb[2*128 + 64 + lane] = aB.z; pb[3*128 + 64 + lane] = aB.w;
  }
}

// ---------------- fused BN2-coeffs + maxpool(relu(BN2(y2))) per batch ----------------
__device__ void f2ab_body(const float* __restrict__ partB, int nb, int bpb, float Pinv,
    const float* __restrict__ g2, const float* __restrict__ be2,
    float* __restrict__ out, int lv, int b) {
  const int ch = threadIdx.x;   // 128 active threads
  float s = 0.f, q = 0.f;
  for (int i = 0; i < nb; i++) {
    s += partB[(size_t)i*512 + ch];
    q += partB[(size_t)i*512 + 128 + ch];
  }
  const float mean = s * Pinv;
  const float var  = fmaxf(q * Pinv - mean*mean, 0.f);
  const float a    = g2[ch] * rsqrtf(var + BN_EPS);
  const float c    = fmaf(-a, mean, be2[ch]);
  const float* pb = partB + (size_t)b * bpb * 512;
  float mx = -1e30f, mn = 1e30f;
  for (int i = 0; i < bpb; i++) {
    mx = fmaxf(mx, pb[(size_t)i*512 + 256 + ch]);
    mn = fminf(mn, pb[(size_t)i*512 + 384 + ch]);
  }
  const float v = (a >= 0.f) ? mx : mn;
  out[b*384 + lv*128 + ch] = fmaxf(0.f, fmaf(a, v, c));
}

// ---------------- level-0 moment reduction (transposed output) ----------------
__global__ __launch_bounds__(256) void mom0_kernel(const float* __restrict__ pts,
                                                   float* __restrict__ mpT) {
  __shared__ float red[256];
  const int tid = threadIdx.x;
  float acc[9] = {0,0,0,0,0,0,0,0,0};
#pragma unroll
  for (int i = 0; i < 4; i++) {
    const size_t j = (size_t)blockIdx.x * 1024 + (size_t)i * 256 + tid;
    const float x = pts[3*j], y = pts[3*j+1], z = pts[3*j+2];
    acc[0]+=x; acc[1]+=y; acc[2]+=z;
    acc[3]=fmaf(x,x,acc[3]); acc[4]=fmaf(y,y,acc[4]); acc[5]=fmaf(z,z,acc[5]);
    acc[6]=fmaf(x,y,acc[6]); acc[7]=fmaf(x,z,acc[7]); acc[8]=fmaf(y,z,acc[8]);
  }
  for (int k = 0; k < 9; k++) {
    red[tid] = acc[k]; __syncthreads();
    for (int s = 128; s > 0; s >>= 1) { if (tid < s) red[tid] += red[tid+s]; __syncthreads(); }
    if (tid == 0) mpT[k*128 + blockIdx.x] = red[0];
    __syncthreads();
  }
}

// ---------------- K_A: blocks 0..63 = fused FPS0+FPS1, rest = feat level-0 ----------------
__global__ __launch_bounds__(256, 2) void kA_kernel(const float* __restrict__ pts,
    const float* __restrict__ momT0, const float* __restrict__ w1,
    const float* __restrict__ g1, const float* __restrict__ be1, const float* __restrict__ w2,
    float* __restrict__ partB0, float* __restrict__ pts1, float* __restrict__ pts2,
    float* __restrict__ momT1, float* __restrict__ momT2) {
  __shared__ SMem sm;
  if (blockIdx.x < 64) { fps_chain(pts, pts1, pts2, momT1, momT2, &sm.fps); return; }
  featB_body<2048, 128>(pts, momT0, 1.f/131072.f, w1, g1, be1, w2, partB0,
                        (int)blockIdx.x - 64, &sm.feat);
}

// ---------------- K_B: feat1 (256) + feat2 (128) + f2ab lv0 (64) ----------------
__global__ __launch_bounds__(256, 2) void kB_kernel(const float* __restrict__ pts1,
    const float* __restrict__ pts2, const float* __restrict__ momT1,
    const float* __restrict__ momT2, const float* __restrict__ w1,
    const float* __restrict__ g1, const float* __restrict__ be1, const float* __restrict__ w2,
    const float* __restrict__ g2, const float* __restrict__ be2,
    float* __restrict__ partB1, float* __restrict__ partB2,
    const float* __restrict__ partB0, float* __restrict__ out) {
  __shared__ SMem sm;
  if (blockIdx.x < 256) {
    featB_body<1024, 64>(pts1, momT1, 1.f/65536.f, w1 + 192, g1 + 64, be1 + 64,
                         w2 + 8192, partB1, (int)blockIdx.x, &sm.feat);
  } else if (blockIdx.x < 384) {
    featB_body<512, 64>(pts2, momT2, 1.f/32768.f, w1 + 384, g1 + 128, be1 + 128,
                        w2 + 16384, partB2, (int)blockIdx.x - 256, &sm.feat);
  } else if (threadIdx.x < 128) {
    f2ab_body(partB0, 512, 8, 1.f/131072.f, g2, be2, out, 0, (int)blockIdx.x - 384);
  }
}

// ---------------- postF: f2ab lv1 (64 blocks) + lv2 (64 blocks) ----------------
__global__ __launch_bounds__(128) void postF_kernel(const float* __restrict__ partB1,
    const float* __restrict__ partB2, const float* __restrict__ g2,
    const float* __restrict__ be2, float* __restrict__ out) {
  if (blockIdx.x < 64) f2ab_body(partB1, 256, 4, 1.f/65536.f, g2 + 128, be2 + 128, out, 1, (int)blockIdx.x);
  else                 f2ab_body(partB2, 128, 2, 1.f/32768.f, g2 + 256, be2 + 256, out, 2, (int)blockIdx.x - 64);
}

// ---------------- host launch ----------------
extern "C" void kernel_launch(void* const* d_in, const int* in_sizes, int n_in,
                              void* d_out, int out_size, void* d_ws, size_t ws_size,
                              hipStream_t stream) {
  const float* pts = (const float*)d_in[0];
  const float* w1  = (const float*)d_in[1];
  const float* g1  = (const float*)d_in[3];
  const float* be1 = (const float*)d_in[4];
  const float* w2  = (const float*)d_in[5];
  const float* g2  = (const float*)d_in[7];
  const float* be2 = (const float*)d_in[8];
  float* out = (float*)d_out;
  float* wsf = (float*)d_ws;

  float* pts1   = wsf;                  // 196608
  float* pts2   = pts1   + 196608;      //  98304
  float* momT0  = pts2   + 98304;       //    1152 (9 x 128, transposed)
  float* momT1  = momT0  + 1152;        //     576 (9 x 64)
  float* momT2  = momT1  + 576;         //     576
  float* partB0 = momT2  + 576;         //  262144 (512 x 512)
  float* partB1 = partB0 + 262144;      //  131072 (256 x 512)
  float* partB2 = partB1 + 131072;      //   65536 (128 x 512)

  mom0_kernel<<<128, 256, 0, stream>>>(pts, momT0);
  kA_kernel<<<64 + 512, 256, 0, stream>>>(pts, momT0, w1, g1, be1, w2,
                                          partB0, pts1, pts2, momT1, momT2);
  kB_kernel<<<256 + 128 + 64, 256, 0, stream>>>(pts1, pts2, momT1, momT2, w1, g1, be1, w2,
                                                g2, be2, partB1, partB2, partB0, out);
  postF_kernel<<<128, 128, 0, stream>>>(partB1, partB2, g2, be2, out);
}

// Round 11
// 687.886 us; speedup vs baseline: 1.4140x; 1.4140x over previous
//
#include <hip/hip_runtime.h>

#define BN_EPS 1e-5f

typedef unsigned long long u64;

// ---------------- shared-memory union ----------------
struct FpsSm {
  u64    slotK[2][4];    // per-wave candidate key {dist_bits,~j}, parity-buffered
  float4 P4[2048];       // packed point coords for winner gather (1 ds_read_b128)
  float  sel1[3 * 1024];
  float  sel2[3 * 512];
};
struct FeatSm {
  float W1s[256];        // folded layer-1 weights: [c][4] = a*w0,a*w1,a*w2, be-a*mean
  float h1s[128][68];    // padded rows (68 floats = 272B, 16B aligned)
  float stat[4][64][8];  // per-wave partial stats
};
union __align__(16) SMem { FpsSm fps; FeatSm feat; };

// ---------------- fast wave-wide reduce (DPP) ----------------
#if __has_builtin(__builtin_amdgcn_update_dpp) && __has_builtin(__builtin_amdgcn_readlane)
template<int CTRL>
__device__ __forceinline__ float dppmax(float x) {
  const int t = __builtin_amdgcn_update_dpp(0, __float_as_int(x), CTRL, 0xf, 0xf, true);
  return fmaxf(x, __int_as_float(t));
}
__device__ __forceinline__ float wave_max_f32(float x) {
  x = dppmax<0x111>(x); x = dppmax<0x112>(x); x = dppmax<0x114>(x);
  x = dppmax<0x118>(x); x = dppmax<0x142>(x); x = dppmax<0x143>(x);
  return __int_as_float(__builtin_amdgcn_readlane(__float_as_int(x), 63));
}
template<int CTRL>
__device__ __forceinline__ float dppsum(float x) {
  const int t = __builtin_amdgcn_update_dpp(0, __float_as_int(x), CTRL, 0xf, 0xf, true);
  return x + __int_as_float(t);
}
__device__ __forceinline__ float wave_sum_f32(float x) {
  x = dppsum<0x111>(x); x = dppsum<0x112>(x); x = dppsum<0x114>(x);
  x = dppsum<0x118>(x); x = dppsum<0x142>(x); x = dppsum<0x143>(x);
  return __int_as_float(__builtin_amdgcn_readlane(__float_as_int(x), 63));
}
#else
__device__ __forceinline__ float wave_max_f32(float x) {
  for (int off = 32; off; off >>= 1) x = fmaxf(x, __shfl_xor(x, off));
  return x;
}
__device__ __forceinline__ float wave_sum_f32(float x) {
  for (int off = 32; off; off >>= 1) x += __shfl_xor(x, off);
  return x;
}
#endif

// ---------------- one FPS phase: 4 waves, barrier exchange, key-only publish ----------------
// (R8 form — serial per-lane scan; do not restructure: compiler interleaves the
//  8 independent distance computes under the compare chain. R9/R10 variants regressed.)
template<int NPTS>
__device__ void fps_phase(const float* __restrict__ src, float* __restrict__ selOut, FpsSm* sm) {
  constexpr int R = NPTS / 256;
  constexpr int M = NPTS / 2;
  const int tid = threadIdx.x;
  const int w   = tid >> 6;

  float px[R], py[R], pz[R], mind[R];
#pragma unroll
  for (int i = 0; i < R; i++) {
    const int j = tid + 256 * i;
    const float x = src[3*j], y = src[3*j+1], z = src[3*j+2];
    px[i] = x; py[i] = y; pz[i] = z;
    sm->P4[j] = make_float4(x, y, z, 0.f);
  }

  float sx = src[0], sy = src[1], sz = src[2];
  if (tid == 0) { selOut[0] = sx; selOut[1] = sy; selOut[2] = sz; }

  float bv = -1.0f; int bi = 0;
#pragma unroll
  for (int i = 0; i < R; i++) {
    const float dx = px[i]-sx, dy = py[i]-sy, dz = pz[i]-sz;
    const float d = __fadd_rn(__fadd_rn(__fmul_rn(dx,dx), __fmul_rn(dy,dy)), __fmul_rn(dz,dz));
    mind[i] = d;
    if (d > bv) { bv = d; bi = i; }     // ascending i == ascending j: first max wins
  }

  for (int it = 1; it < M; ++it) {
    // wave-level: value max via DPP; winner lane self-identifies
    const float smax = wave_max_f32(bv);
    bool win = (bv == smax);
    if (__popcll(__ballot(win)) > 1) {  // exact value ties (rare): lowest global j wins
      int jj = win ? (tid + (bi << 8)) : 0x7fffffff;
#pragma unroll
      for (int off = 32; off; off >>= 1) jj = min(jj, __shfl_xor(jj, off));
      win = win && ((tid + (bi << 8)) == jj);
    }

    // publish: single u64 key {dist_bits, ~j}; dist>=0 so float-bit order == value order
    const int par = it & 1;
    if (win) {
      const unsigned wj = (unsigned)(tid + (bi << 8));
      sm->slotK[par][w] = ((u64)__float_as_uint(bv) << 32) | (u64)(~wj);
    }
    __syncthreads();

    // combine 4 keys (max = farthest; ties -> lowest j), then coords by index
    const uint4 s01 = *reinterpret_cast<const uint4*>(&sm->slotK[par][0]);
    const uint4 s23 = *reinterpret_cast<const uint4*>(&sm->slotK[par][2]);
    const u64 K0 = ((u64)s01.y << 32) | s01.x;
    const u64 K1 = ((u64)s01.w << 32) | s01.z;
    const u64 K2 = ((u64)s23.y << 32) | s23.x;
    const u64 K3 = ((u64)s23.w << 32) | s23.z;
    const u64 Ka = K0 > K1 ? K0 : K1;
    const u64 Kb = K2 > K3 ? K2 : K3;
    const u64 KW = Ka > Kb ? Ka : Kb;
    const unsigned wj = ~(unsigned)(KW & 0xffffffffu);
    const float4 c = sm->P4[wj];        // broadcast ds_read_b128
    sx = c.x; sy = c.y; sz = c.z;

    if (tid == 0) { selOut[3*it] = sx; selOut[3*it+1] = sy; selOut[3*it+2] = sz; }

    // distance update + per-lane argmax scan (serial form — keep)
    bv = -1.0f; bi = 0;
#pragma unroll
    for (int i = 0; i < R; i++) {
      const float dx = px[i]-sx, dy = py[i]-sy, dz = pz[i]-sz;
      const float d = __fadd_rn(__fadd_rn(__fmul_rn(dx,dx), __fmul_rn(dy,dy)), __fmul_rn(dz,dz));
      const float mv = fminf(mind[i], d);
      mind[i] = mv;
      if (mv > bv) { bv = mv; bi = i; }
    }
  }
}

// moments of a selected set in LDS (wave 0 only), stored TRANSPOSED: momT[k*S + b]
__device__ void mom_from_sel(const float* __restrict__ sel, int M, float* __restrict__ momT,
                             int S, int b, int lane) {
  float m0=0.f,m1=0.f,m2=0.f,m3=0.f,m4=0.f,m5=0.f,m6=0.f,m7=0.f,m8=0.f;
  for (int k = lane; k < M; k += 64) {
    const float x = sel[3*k], y = sel[3*k+1], z = sel[3*k+2];
    m0 += x; m1 += y; m2 += z;
    m3 = fmaf(x,x,m3); m4 = fmaf(y,y,m4); m5 = fmaf(z,z,m5);
    m6 = fmaf(x,y,m6); m7 = fmaf(x,z,m7); m8 = fmaf(y,z,m8);
  }
#pragma unroll
  for (int off = 32; off; off >>= 1) {
    m0 += __shfl_xor(m0, off); m1 += __shfl_xor(m1, off); m2 += __shfl_xor(m2, off);
    m3 += __shfl_xor(m3, off); m4 += __shfl_xor(m4, off); m5 += __shfl_xor(m5, off);
    m6 += __shfl_xor(m6, off); m7 += __shfl_xor(m7, off); m8 += __shfl_xor(m8, off);
  }
  if (lane == 0) {
    momT[0*S+b]=m0; momT[1*S+b]=m1; momT[2*S+b]=m2; momT[3*S+b]=m3; momT[4*S+b]=m4;
    momT[5*S+b]=m5; momT[6*S+b]=m6; momT[7*S+b]=m7; momT[8*S+b]=m8;
  }
}

// FPS chain: FPS0 then FPS1 back-to-back; ALL global flushes deferred to the end
// so no vmcnt store-drain sits between the two serial phases.
__device__ void fps_chain(const float* __restrict__ pts, float* __restrict__ pts1,
                          float* __restrict__ pts2, float* __restrict__ momT1,
                          float* __restrict__ momT2, FpsSm* sm) {
  const int b = blockIdx.x, tid = threadIdx.x, lane = tid & 63, w = tid >> 6;
  __builtin_amdgcn_s_setprio(1);

  fps_phase<2048>(pts + (size_t)b * 2048 * 3, sm->sel1, sm);
  __syncthreads();                       // sel1 complete (phase 2 reads it)

  fps_phase<1024>(sm->sel1, sm->sel2, sm);
  __syncthreads();                       // sel2 complete
  __builtin_amdgcn_s_setprio(0);

  {
    float* o1 = pts1 + (size_t)b * 1024 * 3;
#pragma unroll 4
    for (int e = tid; e < 3 * 1024; e += 256) o1[e] = sm->sel1[e];
    float* o2 = pts2 + (size_t)b * 512 * 3;
#pragma unroll 4
    for (int e = tid; e < 3 * 512; e += 256) o2[e] = sm->sel2[e];
    if (w == 0) mom_from_sel(sm->sel1, 1024, momT1, 64, b, lane);
    else if (w == 1) mom_from_sel(sm->sel2, 512, momT2, 64, b, lane);
  }
}

// ---------------- feature pass with inline BN1-fold (fin1) from transposed moments ----------------
template<int NPTS, int S>
__device__ void featB_body(const float* __restrict__ pts, const float* __restrict__ momT,
                           float Pinv, const float* __restrict__ w1lv,
                           const float* __restrict__ g1lv, const float* __restrict__ be1lv,
                           const float* __restrict__ w2lv, float* __restrict__ partialsB,
                           int fbid, FeatSm* sm) {
  const int tid  = threadIdx.x;
  const int lane = tid & 63;
  const int w    = tid >> 6;
  constexpr int BPB = NPTS / 256;
  const int b = fbid / BPB;
  const size_t pbase = (size_t)b * NPTS + (size_t)(fbid % BPB) * 256;

  // wave 0: fold BN1 into weights (9 DPP wave-sums over moment partials)
  if (w == 0) {
    float Mk[9];
#pragma unroll
    for (int k = 0; k < 9; k++) {
      float v = momT[k*S + lane];
      if (S == 128) v += momT[k*S + 64 + lane];
      Mk[k] = wave_sum_f32(v);
    }
    const int t = lane;
    const float w0 = w1lv[t], w1_ = w1lv[64 + t], w2_ = w1lv[128 + t];
    const float mean = (w0*Mk[0] + w1_*Mk[1] + w2_*Mk[2]) * Pinv;
    const float ey2  = (w0*w0*Mk[3] + w1_*w1_*Mk[4] + w2_*w2_*Mk[5]
                      + 2.f*(w0*w1_*Mk[6] + w0*w2_*Mk[7] + w1_*w2_*Mk[8])) * Pinv;
    const float var  = fmaxf(ey2 - mean*mean, 0.f);
    const float a    = g1lv[t] * rsqrtf(var + BN_EPS);
    float4 r; r.x = a*w0; r.y = a*w1_; r.z = a*w2_; r.w = fmaf(-a, mean, be1lv[t]);
    *reinterpret_cast<float4*>(&sm->W1s[t*4]) = r;
  }
  __syncthreads();

  float wA[64], wB[64];
#pragma unroll
  for (int k = 0; k < 64; k++) { wA[k] = w2lv[k*128 + lane]; wB[k] = w2lv[k*128 + 64 + lane]; }

  float sA=0.f, qA=0.f, sB=0.f, qB=0.f;
  float mxA=-1e30f, mnA=1e30f, mxB=-1e30f, mnB=1e30f;

  for (int r = 0; r < 2; r++) {
    __syncthreads();
    if (tid < 128) {
      const float* pp = pts + (pbase + (size_t)r*128 + tid) * 3;
      const float x = pp[0], y = pp[1], z = pp[2];
#pragma unroll
      for (int k = 0; k < 64; k += 4) {
        float4 hv;
        { const float4 wf = *reinterpret_cast<const float4*>(&sm->W1s[4*(k  )]);
          hv.x = fmaxf(0.f, fmaf(x,wf.x, fmaf(y,wf.y, fmaf(z,wf.z, wf.w)))); }
        { const float4 wf = *reinterpret_cast<const float4*>(&sm->W1s[4*(k+1)]);
          hv.y = fmaxf(0.f, fmaf(x,wf.x, fmaf(y,wf.y, fmaf(z,wf.z, wf.w)))); }
        { const float4 wf = *reinterpret_cast<const float4*>(&sm->W1s[4*(k+2)]);
          hv.z = fmaxf(0.f, fmaf(x,wf.x, fmaf(y,wf.y, fmaf(z,wf.z, wf.w)))); }
        { const float4 wf = *reinterpret_cast<const float4*>(&sm->W1s[4*(k+3)]);
          hv.w = fmaxf(0.f, fmaf(x,wf.x, fmaf(y,wf.y, fmaf(z,wf.z, wf.w)))); }
        *reinterpret_cast<float4*>(&sm->h1s[tid][k]) = hv;
      }
    }
    __syncthreads();
    const int row0 = w * 32;
    for (int p = row0; p < row0 + 32; ++p) {
      float ya = 0.f, yb = 0.f;
#pragma unroll
      for (int k = 0; k < 64; k += 4) {
        const float4 hv = *reinterpret_cast<const float4*>(&sm->h1s[p][k]);
        ya = fmaf(hv.x, wA[k  ], ya);  yb = fmaf(hv.x, wB[k  ], yb);
        ya = fmaf(hv.y, wA[k+1], ya);  yb = fmaf(hv.y, wB[k+1], yb);
        ya = fmaf(hv.z, wA[k+2], ya);  yb = fmaf(hv.z, wB[k+2], yb);
        ya = fmaf(hv.w, wA[k+3], ya);  yb = fmaf(hv.w, wB[k+3], yb);
      }
      sA += ya; qA = fmaf(ya,ya,qA); mxA = fmaxf(mxA,ya); mnA = fminf(mnA,ya);
      sB += yb; qB = fmaf(yb,yb,qB); mxB = fmaxf(mxB,yb); mnB = fminf(mnB,yb);
    }
  }

  float4* st = reinterpret_cast<float4*>(&sm->stat[w][lane][0]);
  st[0] = make_float4(sA,qA,mxA,mnA);
  st[1] = make_float4(sB,qB,mxB,mnB);
  __syncthreads();
  if (w == 0) {
    float4 aA = *reinterpret_cast<float4*>(&sm->stat[0][lane][0]);
    float4 aB = *reinterpret_cast<float4*>(&sm->stat[0][lane][4]);
#pragma unroll
    for (int q = 1; q < 4; q++) {
      const float4 cA = *reinterpret_cast<float4*>(&sm->stat[q][lane][0]);
      const float4 cB = *reinterpret_cast<float4*>(&sm->stat[q][lane][4]);
      aA.x += cA.x; aA.y += cA.y; aA.z = fmaxf(aA.z,cA.z); aA.w = fminf(aA.w,cA.w);
      aB.x += cB.x; aB.y += cB.y; aB.z = fmaxf(aB.z,cB.z); aB.w = fminf(aB.w,cB.w);
    }
    float* pb = partialsB + (size_t)fbid * 512;
    pb[0*128 +      lane] = aA.x; pb[1*128 +      lane] = aA.y;
    pb[2*128 +      lane] = aA.z; pb[3*128 +      lane] = aA.w;
    pb[0*128 + 64 + lane] = aB.x; pb[1*128 + 64 + lane] = aB.y;
    pb[2*128 + 64 + lane] = aB.z; pb[3*128 + 64 + lane] = aB.w;
  }
}

// ---------------- fused BN2-coeffs + maxpool(relu(BN2(y2))) per batch ----------------
__device__ void f2ab_body(const float* __restrict__ partB, int nb, int bpb, float Pinv,
    const float* __restrict__ g2, const float* __restrict__ be2,
    float* __restrict__ out, int lv, int b) {
  const int ch = threadIdx.x;   // 128 active threads
  float s = 0.f, q = 0.f;
  for (int i = 0; i < nb; i++) {
    s += partB[(size_t)i*512 + ch];
    q += partB[(size_t)i*512 + 128 + ch];
  }
  const float mean = s * Pinv;
  const float var  = fmaxf(q * Pinv - mean*mean, 0.f);
  const float a    = g2[ch] * rsqrtf(var + BN_EPS);
  const float c    = fmaf(-a, mean, be2[ch]);
  const float* pb = partB + (size_t)b * bpb * 512;
  float mx = -1e30f, mn = 1e30f;
  for (int i = 0; i < bpb; i++) {
    mx = fmaxf(mx, pb[(size_t)i*512 + 256 + ch]);
    mn = fminf(mn, pb[(size_t)i*512 + 384 + ch]);
  }
  const float v = (a >= 0.f) ? mx : mn;
  out[b*384 + lv*128 + ch] = fmaxf(0.f, fmaf(a, v, c));
}

// ---------------- level-0 moment reduction (transposed output) ----------------
__global__ __launch_bounds__(256) void mom0_kernel(const float* __restrict__ pts,
                                                   float* __restrict__ mpT) {
  __shared__ float red[256];
  const int tid = threadIdx.x;
  float acc[9] = {0,0,0,0,0,0,0,0,0};
#pragma unroll
  for (int i = 0; i < 4; i++) {
    const size_t j = (size_t)blockIdx.x * 1024 + (size_t)i * 256 + tid;
    const float x = pts[3*j], y = pts[3*j+1], z = pts[3*j+2];
    acc[0]+=x; acc[1]+=y; acc[2]+=z;
    acc[3]=fmaf(x,x,acc[3]); acc[4]=fmaf(y,y,acc[4]); acc[5]=fmaf(z,z,acc[5]);
    acc[6]=fmaf(x,y,acc[6]); acc[7]=fmaf(x,z,acc[7]); acc[8]=fmaf(y,z,acc[8]);
  }
  for (int k = 0; k < 9; k++) {
    red[tid] = acc[k]; __syncthreads();
    for (int s = 128; s > 0; s >>= 1) { if (tid < s) red[tid] += red[tid+s]; __syncthreads(); }
    if (tid == 0) mpT[k*128 + blockIdx.x] = red[0];
    __syncthreads();
  }
}

// ---------------- K_A: blocks 0..63 = fused FPS0+FPS1, rest = feat level-0 ----------------
__global__ __launch_bounds__(256, 2) void kA_kernel(const float* __restrict__ pts,
    const float* __restrict__ momT0, const float* __restrict__ w1,
    const float* __restrict__ g1, const float* __restrict__ be1, const float* __restrict__ w2,
    float* __restrict__ partB0, float* __restrict__ pts1, float* __restrict__ pts2,
    float* __restrict__ momT1, float* __restrict__ momT2) {
  __shared__ SMem sm;
  if (blockIdx.x < 64) { fps_chain(pts, pts1, pts2, momT1, momT2, &sm.fps); return; }
  featB_body<2048, 128>(pts, momT0, 1.f/131072.f, w1, g1, be1, w2, partB0,
                        (int)blockIdx.x - 64, &sm.feat);
}

// ---------------- K_B: feat1 (256) + feat2 (128) + f2ab lv0 (64) ----------------
__global__ __launch_bounds__(256, 2) void kB_kernel(const float* __restrict__ pts1,
    const float* __restrict__ pts2, const float* __restrict__ momT1,
    const float* __restrict__ momT2, const float* __restrict__ w1,
    const float* __restrict__ g1, const float* __restrict__ be1, const float* __restrict__ w2,
    const float* __restrict__ g2, const float* __restrict__ be2,
    float* __restrict__ partB1, float* __restrict__ partB2,
    const float* __restrict__ partB0, float* __restrict__ out) {
  __shared__ SMem sm;
  if (blockIdx.x < 256) {
    featB_body<1024, 64>(pts1, momT1, 1.f/65536.f, w1 + 192, g1 + 64, be1 + 64,
                         w2 + 8192, partB1, (int)blockIdx.x, &sm.feat);
  } else if (blockIdx.x < 384) {
    featB_body<512, 64>(pts2, momT2, 1.f/32768.f, w1 + 384, g1 + 128, be1 + 128,
                        w2 + 16384, partB2, (int)blockIdx.x - 256, &sm.feat);
  } else if (threadIdx.x < 128) {
    f2ab_body(partB0, 512, 8, 1.f/131072.f, g2, be2, out, 0, (int)blockIdx.x - 384);
  }
}

// ---------------- postF: f2ab lv1 (64 blocks) + lv2 (64 blocks) ----------------
__global__ __launch_bounds__(128) void postF_kernel(const float* __restrict__ partB1,
    const float* __restrict__ partB2, const float* __restrict__ g2,
    const float* __restrict__ be2, float* __restrict__ out) {
  if (blockIdx.x < 64) f2ab_body(partB1, 256, 4, 1.f/65536.f, g2 + 128, be2 + 128, out, 1, (int)blockIdx.x);
  else                 f2ab_body(partB2, 128, 2, 1.f/32768.f, g2 + 256, be2 + 256, out, 2, (int)blockIdx.x - 64);
}

// ---------------- host launch ----------------
extern "C" void kernel_launch(void* const* d_in, const int* in_sizes, int n_in,
                              void* d_out, int out_size, void* d_ws, size_t ws_size,
                              hipStream_t stream) {
  const float* pts = (const float*)d_in[0];
  const float* w1  = (const float*)d_in[1];
  const float* g1  = (const float*)d_in[3];
  const float* be1 = (const float*)d_in[4];
  const float* w2  = (const float*)d_in[5];
  const float* g2  = (const float*)d_in[7];
  const float* be2 = (const float*)d_in[8];
  float* out = (float*)d_out;
  float* wsf = (float*)d_ws;

  float* pts1   = wsf;                  // 196608
  float* pts2   = pts1   + 196608;      //  98304
  float* momT0  = pts2   + 98304;       //    1152 (9 x 128, transposed)
  float* momT1  = momT0  + 1152;        //     576 (9 x 64)
  float* momT2  = momT1  + 576;         //     576
  float* partB0 = momT2  + 576;         //  262144 (512 x 512)
  float* partB1 = partB0 + 262144;      //  131072 (256 x 512)
  float* partB2 = partB1 + 131072;      //   65536 (128 x 512)

  mom0_kernel<<<128, 256, 0, stream>>>(pts, momT0);
  kA_kernel<<<64 + 512, 256, 0, stream>>>(pts, momT0, w1, g1, be1, w2,
                                          partB0, pts1, pts2, momT1, momT2);
  kB_kernel<<<256 + 128 + 64, 256, 0, stream>>>(pts1, pts2, momT1, momT2, w1, g1, be1, w2,
                                                g2, be2, partB1, partB2, partB0, out);
  postF_kernel<<<128, 128, 0, stream>>>(partB1, partB2, g2, be2, out);
}